// Round 14
// baseline (370.907 us; speedup 1.0000x reference)
//
#include <hip/hip_runtime.h>
#include <math.h>

#define N_USERS_C 100000
#define N_ITEMS_C 50000
#define N_NODES_C 150000
#define N_EDGES_C 2000000
#define N_ENTRIES_C 4000000
#define DIM_C 64
#define DECAY_C 1e-4f
#define BATCH_C 4096

#define TILE_EDGES 2048
#define NTILES ((N_EDGES_C + TILE_EDGES - 1) / TILE_EDGES)   // 977

// 512 entry-balanced buckets: 256 user buckets x 391 nodes, 256 item x 196.
#define UB_NODES 391
#define IB_NODES 196
#define NBUCK 512
#define B1_DEPTH 14

#define LOSS_NB (BATCH_C / 4)  // 1024 blocks, 4 batch elems (waves) each

// ws layout (4-byte units):
//   off[150032] | bcnt[512] | bucketStart[520] | cursB1[512] | acc[24] |
//   wfrag[6144] | part[2048] | entP[4M ints] | bf16 tables (4.8M ints)
#define WS_OFF 0
#define WS_BCNT 150032
#define WS_BSTART 150544
#define WS_CB1 151064
#define WS_ACC 151576
#define WS_WFRAG 151600
#define WS_PART 157744
#define WS_ENT 159792
#define WS_BF16 4159792
// total 8,959,792 ints = 35.84 MB

// ent1 staging (int2 AoS, f32 val) in d_out tail floats [30.4M, 38.4M),
// consumed by part2 before gather/transform overwrite that region.
#define ENT1_FLOAT_OFF 30400000

typedef __attribute__((ext_vector_type(8))) short short8v;
typedef __attribute__((ext_vector_type(4))) float f32x4;

__device__ __forceinline__ unsigned bf16_bits(float v) {
  unsigned u = __float_as_uint(v);
  return (u + 0x8000u) >> 16;
}

__device__ __forceinline__ short8v as_short8(uint4 u) {
  union { uint4 u4; short8v s8; } x;
  x.u4 = u;
  return x.s8;
}

// ---------------------------------------------------------------------------
// Kernel 0: cast both tables to bf16 (user table then item table, contiguous)
// ---------------------------------------------------------------------------
__global__ __launch_bounds__(256) void cast_kernel(
    const float* __restrict__ user_emb, const float* __restrict__ item_emb,
    ushort* __restrict__ h) {
  const int t = blockIdx.x * 256 + threadIdx.x;  // one float4 per thread
  const int nUser4 = N_USERS_C * DIM_C / 4;
  const int nTot4 = (N_USERS_C + N_ITEMS_C) * DIM_C / 4;
  if (t >= nTot4) return;
  float4 v = (t < nUser4) ? ((const float4*)user_emb)[t]
                          : ((const float4*)item_emb)[t - nUser4];
  ushort4 o;
  o.x = (ushort)bf16_bits(v.x);
  o.y = (ushort)bf16_bits(v.y);
  o.z = (ushort)bf16_bits(v.z);
  o.w = (ushort)bf16_bits(v.w);
  *(ushort4*)&h[(size_t)t * 4] = o;
}

// ---------------------------------------------------------------------------
// Kernel 0b: pack W into 24 MFMA B-fragments (bf16).
// ---------------------------------------------------------------------------
__global__ __launch_bounds__(256) void wprep_kernel(
    const float* __restrict__ W, uint4* __restrict__ wfrag) {
  const int g = blockIdx.x * 256 + threadIdx.x;
  if (g >= 24 * 64) return;
  const int f = g >> 6, l = g & 63;
  const int layer = f >> 3, rem = f & 7, t = rem >> 1, s = rem & 1;
  const int n = t * 16 + (l & 15);
  const int k0 = s * 32 + (l >> 4) * 8;
  const float* base = W + layer * DIM_C * DIM_C + n;  // stride 64 per k
  unsigned r[4];
  #pragma unroll
  for (int j = 0; j < 4; ++j) {
    unsigned lo = bf16_bits(base[(size_t)(k0 + 2 * j) * DIM_C]);
    unsigned hi = bf16_bits(base[(size_t)(k0 + 2 * j + 1) * DIM_C]);
    r[j] = lo | (hi << 16);
  }
  wfrag[g] = make_uint4(r[0], r[1], r[2], r[3]);
}

// ---------------------------------------------------------------------------
// Kernel 1: bucket-level histogram (512 bins, LDS-aggregated)
// ---------------------------------------------------------------------------
__global__ __launch_bounds__(256) void bucket_hist_kernel(
    const int* __restrict__ edge_row, const int* __restrict__ edge_col,
    int* __restrict__ bcnt) {
  __shared__ int h[NBUCK];
  const int tid = threadIdx.x;
  for (int i = tid; i < NBUCK; i += 256) h[i] = 0;
  __syncthreads();
  const int base = blockIdx.x * TILE_EDGES;
  #pragma unroll
  for (int k = 0; k < 8; ++k) {
    int e = base + k * 256 + tid;
    if (e < N_EDGES_C) {
      atomicAdd(&h[(int)((unsigned)edge_row[e] / UB_NODES)], 1);
      atomicAdd(&h[256 + (int)((unsigned)edge_col[e] / IB_NODES)], 1);
    }
  }
  __syncthreads();
  for (int i = tid; i < NBUCK; i += 256) {
    int v = h[i];
    if (v) atomicAdd(&bcnt[i], v);
  }
}

// ---------------------------------------------------------------------------
// Kernel 2: exclusive scan of 512 bucket counts (single block)
// ---------------------------------------------------------------------------
__global__ __launch_bounds__(512) void scan512_kernel(
    const int* __restrict__ bcnt, int* __restrict__ bucketStart,
    int* __restrict__ cursB1) {
  __shared__ int ts[512];
  const int t = threadIdx.x;
  int c = bcnt[t];
  ts[t] = c;
  __syncthreads();
  #pragma unroll
  for (int o = 1; o < 512; o <<= 1) {
    int y = (t >= o) ? ts[t - o] : 0;
    __syncthreads();
    ts[t] += y;
    __syncthreads();
  }
  int excl = ts[t] - c;
  bucketStart[t] = excl;
  cursB1[t] = excl;
  if (t == 511) bucketStart[512] = ts[511];
}

// ---------------------------------------------------------------------------
// Phase B1 (AoS int2): bin entries into 512 buckets.
// ent1 packing: x = src | (local_node << 17), y = f32 val bits.
// ---------------------------------------------------------------------------
__global__ __launch_bounds__(256) void part1_kernel(
    const int* __restrict__ edge_row, const int* __restrict__ edge_col,
    const float* __restrict__ edge_val, int* __restrict__ cursB1,
    int2* __restrict__ ent1) {
  __shared__ int2 stg[NBUCK][B1_DEPTH];  // 56 KB
  __shared__ int scnt[NBUCK];
  const int tid = threadIdx.x;
  for (int i = tid; i < NBUCK; i += 256) scnt[i] = 0;
  __syncthreads();

  const int base = blockIdx.x * TILE_EDGES;
  #pragma unroll
  for (int k = 0; k < 8; ++k) {
    int e = base + k * 256 + tid;
    if (e < N_EDGES_C) {
      int r = edge_row[e];
      int c = edge_col[e];
      int vb = __float_as_int(edge_val[e]);
      int ub = (int)((unsigned)r / UB_NODES);
      int2 E1 = make_int2(c | ((r - ub * UB_NODES) << 17), vb);
      int s1 = atomicAdd(&scnt[ub], 1);
      if (s1 < B1_DEPTH) stg[ub][s1] = E1;
      else ent1[atomicAdd(&cursB1[ub], 1)] = E1;
      int ib = (int)((unsigned)c / IB_NODES);
      int2 E2 = make_int2(r | ((c - ib * IB_NODES) << 17), vb);
      ib += 256;
      int s2 = atomicAdd(&scnt[ib], 1);
      if (s2 < B1_DEPTH) stg[ib][s2] = E2;
      else ent1[atomicAdd(&cursB1[ib], 1)] = E2;
    }
  }
  __syncthreads();
  for (int i = tid; i < NBUCK; i += 256) {
    int cn = scnt[i];
    if (cn > B1_DEPTH) cn = B1_DEPTH;
    if (cn) {
      int p = atomicAdd(&cursB1[i], cn);
      for (int j = 0; j < cn; ++j) ent1[p + j] = stg[i][j];
    }
  }
}

// ---------------------------------------------------------------------------
// Phase B2: per-bucket node histogram + LDS scan -> off[] coalesced;
// scatter packed 4B entries via LDS cursor atomics.
// user-dest: P = (bf16(val)<<16) | src16
// item-dest: P = ((bf16(val)&0xFFFE | src&1)<<16) | (src>>1)
// ---------------------------------------------------------------------------
__global__ __launch_bounds__(256) void part2_kernel(
    const int* __restrict__ bucketStart, const int2* __restrict__ ent1,
    int* __restrict__ off, unsigned* __restrict__ entP) {
  __shared__ int lhist[512];
  __shared__ int lexcl[512];
  __shared__ int ps[256];
  const int b = blockIdx.x;
  const int tid = threadIdx.x;
  int nb, nodes;
  if (b < 256) {
    nb = b * UB_NODES;
    int e = (b + 1) * UB_NODES;
    if (e > N_USERS_C) e = N_USERS_C;
    nodes = e - nb;
  } else {
    nb = N_USERS_C + (b - 256) * IB_NODES;
    int e = N_USERS_C + (b - 255) * IB_NODES;
    if (e > N_NODES_C) e = N_NODES_C;
    nodes = e - nb;
  }
  const int start = bucketStart[b];
  const int end = bucketStart[b + 1];

  for (int i = tid; i < 512; i += 256) lhist[i] = 0;
  __syncthreads();

  for (int i = start + tid; i < end; i += 256)
    atomicAdd(&lhist[(unsigned)ent1[i].x >> 17], 1);
  __syncthreads();

  int a0 = lhist[2 * tid];
  int a1 = lhist[2 * tid + 1];
  ps[tid] = a0 + a1;
  __syncthreads();
  #pragma unroll
  for (int o = 1; o < 256; o <<= 1) {
    int y = (tid >= o) ? ps[tid - o] : 0;
    __syncthreads();
    ps[tid] += y;
    __syncthreads();
  }
  int e0 = ps[tid] - a0 - a1;
  lexcl[2 * tid] = e0;
  lexcl[2 * tid + 1] = e0 + a0;
  __syncthreads();

  for (int t = tid; t < nodes; t += 256) off[nb + t] = start + lexcl[t];
  if (b == NBUCK - 1 && tid == 0) off[N_NODES_C] = N_ENTRIES_C;

  for (int i = tid; i < 512; i += 256) lhist[i] = lexcl[i];
  __syncthreads();

  const bool isUser = (b < 256);
  for (int i = start + tid; i < end; i += 256) {
    int2 E = ent1[i];
    int local = (int)((unsigned)E.x >> 17);
    int src = E.x & 0x1FFFF;
    unsigned hb = bf16_bits(__int_as_float(E.y));
    unsigned P;
    if (isUser) {
      P = (hb << 16) | (unsigned)src;
    } else {
      P = (((hb & 0xFFFEu) | ((unsigned)src & 1u)) << 16) |
          ((unsigned)src >> 1);
    }
    int p = start + atomicAdd(&lhist[local], 1);
    entP[p] = P;
  }
}

// ---------------------------------------------------------------------------
// Gather: octet-wave, 16 rows in flight per wave. entP via nontemporal
// loads (stream-once; keeps bf16 table lines resident in L2).
// Writes bf16 agg row into out's ego slot at float offset +4.
// ---------------------------------------------------------------------------
__device__ __forceinline__ void acc_row8(float* __restrict__ a, unsigned E,
                                         bool isUser,
                                         const ushort* __restrict__ tblU,
                                         const ushort* __restrict__ tblI,
                                         int ol) {
  unsigned src;
  float v;
  const ushort* t;
  if (isUser) {  // uniform branch per node
    src = E & 0xFFFFu;
    v = __uint_as_float(E & 0xFFFF0000u);
    t = tblI;
  } else {
    src = ((E & 0xFFFFu) << 1) | ((E >> 16) & 1u);
    v = __uint_as_float(E & 0xFFFE0000u);
    t = tblU;
  }
  uint4 q = *(const uint4*)(t + ((size_t)src << 6) + (ol << 3));
  a[0] += v * __uint_as_float(q.x << 16);
  a[1] += v * __uint_as_float(q.x & 0xFFFF0000u);
  a[2] += v * __uint_as_float(q.y << 16);
  a[3] += v * __uint_as_float(q.y & 0xFFFF0000u);
  a[4] += v * __uint_as_float(q.z << 16);
  a[5] += v * __uint_as_float(q.z & 0xFFFF0000u);
  a[6] += v * __uint_as_float(q.w << 16);
  a[7] += v * __uint_as_float(q.w & 0xFFFF0000u);
}

__global__ __launch_bounds__(256) void gather_kernel(
    const ushort* __restrict__ bf16tab, const int* __restrict__ off,
    const unsigned* __restrict__ entP, float* __restrict__ out) {
  const int lane = threadIdx.x & 63;
  const int og = lane >> 3;
  const int ol = lane & 7;
  const int wave0 = (blockIdx.x * 256 + threadIdx.x) >> 6;
  const int nWaves = gridDim.x * 4;
  const ushort* tblU = bf16tab;
  const ushort* tblI = bf16tab + (size_t)N_USERS_C * DIM_C;

  for (int n = wave0; n < N_NODES_C; n += nWaves) {
    const bool isUser = (n < N_USERS_C);
    int i = off[n] + og;
    const int end = off[n + 1];
    float a[8] = {0.f, 0.f, 0.f, 0.f, 0.f, 0.f, 0.f, 0.f};
    for (; i + 8 < end; i += 16) {
      unsigned E0 = __builtin_nontemporal_load(&entP[i]);
      unsigned E1 = __builtin_nontemporal_load(&entP[i + 8]);
      acc_row8(a, E0, isUser, tblU, tblI, ol);
      acc_row8(a, E1, isUser, tblU, tblI, ol);
    }
    if (i < end) {
      unsigned E0 = __builtin_nontemporal_load(&entP[i]);
      acc_row8(a, E0, isUser, tblU, tblI, ol);
    }

    #pragma unroll
    for (int k = 0; k < 8; ++k) {
      a[k] += __shfl_xor(a[k], 8);
      a[k] += __shfl_xor(a[k], 16);
      a[k] += __shfl_xor(a[k], 32);
    }
    if (lane < 8) {
      uint4 o;
      o.x = bf16_bits(a[0]) | (bf16_bits(a[1]) << 16);
      o.y = bf16_bits(a[2]) | (bf16_bits(a[3]) << 16);
      o.z = bf16_bits(a[4]) | (bf16_bits(a[5]) << 16);
      o.w = bf16_bits(a[6]) | (bf16_bits(a[7]) << 16);
      ((uint4*)(out + 4 + (size_t)n * 256))[ol] = o;
    }
  }
}

// ---------------------------------------------------------------------------
// Transform (MFMA): wave = 16 nodes, 24 MFMA, in-register epilogue.
// Outputs via nontemporal stores (only loss's sparse sample reads them).
// ---------------------------------------------------------------------------
__global__ __launch_bounds__(256) void transform_kernel(
    const float* __restrict__ user_emb, const float* __restrict__ item_emb,
    const uint4* __restrict__ wfragG, const float* __restrict__ bvec,
    float* __restrict__ out) {
  __shared__ uint4 Wf[24 * 64];  // 24 KB
  const int tid = threadIdx.x;
  for (int i = tid; i < 24 * 64; i += 256) Wf[i] = wfragG[i];
  __syncthreads();

  const int wave = tid >> 6;
  const int lane = tid & 63;
  const int nb = blockIdx.x * 64 + wave * 16;
  if (nb >= N_NODES_C) return;  // whole-wave guard (150000 % 16 == 0)
  const int q = lane >> 4;
  const int col = lane & 15;

  const uint4* aggp = (const uint4*)(out + 4 + (size_t)(nb + col) * 256);
  short8v A0 = as_short8(aggp[q]);
  short8v A1 = as_short8(aggp[q + 4]);

  for (int l = 0; l < 3; ++l) {
    f32x4 c[4];
    #pragma unroll
    for (int t = 0; t < 4; ++t) c[t] = (f32x4){0.f, 0.f, 0.f, 0.f};
    const uint4* wl = &Wf[l * 8 * 64];
    #pragma unroll
    for (int t = 0; t < 4; ++t) {
      c[t] = __builtin_amdgcn_mfma_f32_16x16x32_bf16(
          A0, as_short8(wl[(t * 2 + 0) * 64 + lane]), c[t], 0, 0, 0);
      c[t] = __builtin_amdgcn_mfma_f32_16x16x32_bf16(
          A1, as_short8(wl[(t * 2 + 1) * 64 + lane]), c[t], 0, 0, 0);
    }

    float sq[4] = {0.f, 0.f, 0.f, 0.f};
    #pragma unroll
    for (int t = 0; t < 4; ++t) {
      const float bt = bvec[l * DIM_C + t * 16 + col];
      #pragma unroll
      for (int r = 0; r < 4; ++r) {
        float v = c[t][r] + bt;
        v = (v >= 0.f) ? v : 0.2f * v;
        c[t][r] = v;
        sq[r] += v * v;
      }
    }
    #pragma unroll
    for (int r = 0; r < 4; ++r) {
      #pragma unroll
      for (int m = 1; m < 16; m <<= 1) sq[r] += __shfl_xor(sq[r], m);
      sq[r] = 1.0f / fmaxf(sqrtf(sq[r]), 1e-12f);
    }
    #pragma unroll
    for (int t = 0; t < 4; ++t) {
      #pragma unroll
      for (int r = 0; r < 4; ++r) {
        const int node = nb + q * 4 + r;
        __builtin_nontemporal_store(
            c[t][r] * sq[r],
            &out[1 + (size_t)node * 256 + (size_t)(l + 1) * 64 + t * 16 + col]);
      }
    }
  }

  for (int idx = lane; idx < 16 * DIM_C; idx += 64) {
    const int node = nb + (idx >> 6);
    const int cc = idx & 63;
    float e = (node < N_USERS_C)
                  ? user_emb[(size_t)node * DIM_C + cc]
                  : item_emb[(size_t)(node - N_USERS_C) * DIM_C + cc];
    __builtin_nontemporal_store(e, &out[1 + (size_t)node * 256 + cc]);
  }
}

// ---------------------------------------------------------------------------
// Loss: one wave per batch element; block-level LDS reduction; per-block
// partials to ws (NO global atomics).
// ---------------------------------------------------------------------------
__global__ __launch_bounds__(256) void loss_kernel(
    const float* __restrict__ out, const int* __restrict__ bu,
    const int* __restrict__ bp, const int* __restrict__ bn,
    float* __restrict__ part) {
  __shared__ float smf[4];
  __shared__ float srg[4];
  const int wave = threadIdx.x >> 6;
  const int lane = threadIdx.x & 63;
  const int j = blockIdx.x * 4 + wave;

  const float* urow = out + 1 + (size_t)bu[j] * 256;
  const float* prow = out + 1 + ((size_t)N_USERS_C + bp[j]) * 256;
  const float* nrow = out + 1 + ((size_t)N_USERS_C + bn[j]) * 256;

  float4 u = ((const float4*)urow)[lane];
  float4 pp = ((const float4*)prow)[lane];
  float4 nn = ((const float4*)nrow)[lane];

  float x = u.x * (pp.x - nn.x) + u.y * (pp.y - nn.y) +
            u.z * (pp.z - nn.z) + u.w * (pp.w - nn.w);
  float r = u.x * u.x + u.y * u.y + u.z * u.z + u.w * u.w +
            pp.x * pp.x + pp.y * pp.y + pp.z * pp.z + pp.w * pp.w +
            nn.x * nn.x + nn.y * nn.y + nn.z * nn.z + nn.w * nn.w;

  #pragma unroll
  for (int o = 32; o; o >>= 1) {
    x += __shfl_xor(x, o);
    r += __shfl_xor(r, o);
  }
  if (lane == 0) {
    float ls = fminf(x, 0.f) - log1pf(expf(-fabsf(x)));
    smf[wave] = -ls;
    srg[wave] = 0.5f * r;
  }
  __syncthreads();
  if (threadIdx.x == 0) {
    part[blockIdx.x] = smf[0] + smf[1] + smf[2] + smf[3];
    part[LOSS_NB + blockIdx.x] = srg[0] + srg[1] + srg[2] + srg[3];
  }
}

// ---------------------------------------------------------------------------
// Finalize: single block reduces 2x1024 partials -> out[0]
// ---------------------------------------------------------------------------
__global__ __launch_bounds__(256) void finalize_kernel(
    const float* __restrict__ part, float* __restrict__ out) {
  __shared__ float smf[4];
  __shared__ float srg[4];
  const int tid = threadIdx.x;
  float mf = 0.f, rg = 0.f;
  #pragma unroll
  for (int k = 0; k < LOSS_NB / 256; ++k) {
    mf += part[tid + k * 256];
    rg += part[LOSS_NB + tid + k * 256];
  }
  #pragma unroll
  for (int o = 32; o; o >>= 1) {
    mf += __shfl_xor(mf, o);
    rg += __shfl_xor(rg, o);
  }
  if ((tid & 63) == 0) {
    smf[tid >> 6] = mf;
    srg[tid >> 6] = rg;
  }
  __syncthreads();
  if (tid == 0) {
    float m = smf[0] + smf[1] + smf[2] + smf[3];
    float g = srg[0] + srg[1] + srg[2] + srg[3];
    out[0] = m / (float)BATCH_C + DECAY_C * g / (float)BATCH_C;
  }
}

// ---------------------------------------------------------------------------
extern "C" void kernel_launch(void* const* d_in, const int* in_sizes, int n_in,
                              void* d_out, int out_size, void* d_ws, size_t ws_size,
                              hipStream_t stream) {
  const float* user_emb = (const float*)d_in[0];
  const float* item_emb = (const float*)d_in[1];
  const float* edge_val = (const float*)d_in[2];
  const float* W        = (const float*)d_in[3];
  const float* bvec     = (const float*)d_in[4];
  const int* edge_row   = (const int*)d_in[5];
  const int* edge_col   = (const int*)d_in[6];
  const int* bu         = (const int*)d_in[7];
  const int* bp         = (const int*)d_in[8];
  const int* bn         = (const int*)d_in[9];

  float* out = (float*)d_out;
  int* ws = (int*)d_ws;
  int* off         = ws + WS_OFF;
  int* bcnt        = ws + WS_BCNT;
  int* bucketStart = ws + WS_BSTART;
  int* cursB1      = ws + WS_CB1;
  uint4* wfrag     = (uint4*)(ws + WS_WFRAG);
  float* part      = (float*)(ws + WS_PART);
  unsigned* entP   = (unsigned*)(ws + WS_ENT);
  ushort* bf16tab  = (ushort*)(ws + WS_BF16);
  int2* ent1       = (int2*)(out + ENT1_FLOAT_OFF);

  hipMemsetAsync(bcnt, 0, NBUCK * sizeof(int), stream);

  cast_kernel<<<(2400000 + 255) / 256, 256, 0, stream>>>(user_emb, item_emb,
                                                         bf16tab);
  wprep_kernel<<<6, 256, 0, stream>>>(W, wfrag);
  bucket_hist_kernel<<<NTILES, 256, 0, stream>>>(edge_row, edge_col, bcnt);
  scan512_kernel<<<1, 512, 0, stream>>>(bcnt, bucketStart, cursB1);
  part1_kernel<<<NTILES, 256, 0, stream>>>(edge_row, edge_col, edge_val,
                                           cursB1, ent1);
  part2_kernel<<<NBUCK, 256, 0, stream>>>(bucketStart, ent1, off, entP);
  gather_kernel<<<2048, 256, 0, stream>>>(bf16tab, off, entP, out);
  transform_kernel<<<(N_NODES_C + 63) / 64, 256, 0, stream>>>(
      user_emb, item_emb, wfrag, bvec, out);
  loss_kernel<<<LOSS_NB, 256, 0, stream>>>(out, bu, bp, bn, part);
  finalize_kernel<<<1, 256, 0, stream>>>(part, out);
}

// Round 15
// 287.284 us; speedup vs baseline: 1.2911x; 1.2911x over previous
//
#include <hip/hip_runtime.h>
#include <math.h>

#define N_USERS_C 100000
#define N_ITEMS_C 50000
#define N_NODES_C 150000
#define N_EDGES_C 2000000
#define N_ENTRIES_C 4000000
#define DIM_C 64
#define DECAY_C 1e-4f
#define BATCH_C 4096

#define TILE_EDGES 2048
#define NTILES ((N_EDGES_C + TILE_EDGES - 1) / TILE_EDGES)   // 977

// 512 entry-balanced buckets: 256 user buckets x 391 nodes, 256 item x 196.
#define UB_NODES 391
#define IB_NODES 196
#define NBUCK 512
#define B1_DEPTH 14

#define LOSS_NB (BATCH_C / 4)  // 1024 blocks, 4 batch elems (waves) each

// ws layout (4-byte units):
//   off[150032] | bcnt[512] | bucketStart[520] | cursB1[512] | acc[24] |
//   wfrag[6144] | part[2048] | entP[4M ints] | bf16 tables (4.8M ints)
#define WS_OFF 0
#define WS_BCNT 150032
#define WS_BSTART 150544
#define WS_CB1 151064
#define WS_ACC 151576
#define WS_WFRAG 151600
#define WS_PART 157744
#define WS_ENT 159792
#define WS_BF16 4159792
// total 8,959,792 ints = 35.84 MB

// ent1 staging (int2 AoS, f32 val) in d_out tail floats [30.4M, 38.4M),
// consumed by part2 before gather/transform overwrite that region.
#define ENT1_FLOAT_OFF 30400000

typedef __attribute__((ext_vector_type(8))) short short8v;
typedef __attribute__((ext_vector_type(4))) float f32x4;

__device__ __forceinline__ unsigned bf16_bits(float v) {
  unsigned u = __float_as_uint(v);
  return (u + 0x8000u) >> 16;
}

__device__ __forceinline__ short8v as_short8(uint4 u) {
  union { uint4 u4; short8v s8; } x;
  x.u4 = u;
  return x.s8;
}

// ---------------------------------------------------------------------------
// Kernel 0: cast both tables to bf16 (user table then item table, contiguous)
// ---------------------------------------------------------------------------
__global__ __launch_bounds__(256) void cast_kernel(
    const float* __restrict__ user_emb, const float* __restrict__ item_emb,
    ushort* __restrict__ h) {
  const int t = blockIdx.x * 256 + threadIdx.x;  // one float4 per thread
  const int nUser4 = N_USERS_C * DIM_C / 4;
  const int nTot4 = (N_USERS_C + N_ITEMS_C) * DIM_C / 4;
  if (t >= nTot4) return;
  float4 v = (t < nUser4) ? ((const float4*)user_emb)[t]
                          : ((const float4*)item_emb)[t - nUser4];
  ushort4 o;
  o.x = (ushort)bf16_bits(v.x);
  o.y = (ushort)bf16_bits(v.y);
  o.z = (ushort)bf16_bits(v.z);
  o.w = (ushort)bf16_bits(v.w);
  *(ushort4*)&h[(size_t)t * 4] = o;
}

// ---------------------------------------------------------------------------
// Kernel 0b: pack W into 24 MFMA B-fragments (bf16).
// ---------------------------------------------------------------------------
__global__ __launch_bounds__(256) void wprep_kernel(
    const float* __restrict__ W, uint4* __restrict__ wfrag) {
  const int g = blockIdx.x * 256 + threadIdx.x;
  if (g >= 24 * 64) return;
  const int f = g >> 6, l = g & 63;
  const int layer = f >> 3, rem = f & 7, t = rem >> 1, s = rem & 1;
  const int n = t * 16 + (l & 15);
  const int k0 = s * 32 + (l >> 4) * 8;
  const float* base = W + layer * DIM_C * DIM_C + n;  // stride 64 per k
  unsigned r[4];
  #pragma unroll
  for (int j = 0; j < 4; ++j) {
    unsigned lo = bf16_bits(base[(size_t)(k0 + 2 * j) * DIM_C]);
    unsigned hi = bf16_bits(base[(size_t)(k0 + 2 * j + 1) * DIM_C]);
    r[j] = lo | (hi << 16);
  }
  wfrag[g] = make_uint4(r[0], r[1], r[2], r[3]);
}

// ---------------------------------------------------------------------------
// Kernel 1: bucket-level histogram (512 bins, LDS-aggregated)
// ---------------------------------------------------------------------------
__global__ __launch_bounds__(256) void bucket_hist_kernel(
    const int* __restrict__ edge_row, const int* __restrict__ edge_col,
    int* __restrict__ bcnt) {
  __shared__ int h[NBUCK];
  const int tid = threadIdx.x;
  for (int i = tid; i < NBUCK; i += 256) h[i] = 0;
  __syncthreads();
  const int base = blockIdx.x * TILE_EDGES;
  #pragma unroll
  for (int k = 0; k < 8; ++k) {
    int e = base + k * 256 + tid;
    if (e < N_EDGES_C) {
      atomicAdd(&h[(int)((unsigned)edge_row[e] / UB_NODES)], 1);
      atomicAdd(&h[256 + (int)((unsigned)edge_col[e] / IB_NODES)], 1);
    }
  }
  __syncthreads();
  for (int i = tid; i < NBUCK; i += 256) {
    int v = h[i];
    if (v) atomicAdd(&bcnt[i], v);
  }
}

// ---------------------------------------------------------------------------
// Kernel 2: exclusive scan of 512 bucket counts (single block)
// ---------------------------------------------------------------------------
__global__ __launch_bounds__(512) void scan512_kernel(
    const int* __restrict__ bcnt, int* __restrict__ bucketStart,
    int* __restrict__ cursB1) {
  __shared__ int ts[512];
  const int t = threadIdx.x;
  int c = bcnt[t];
  ts[t] = c;
  __syncthreads();
  #pragma unroll
  for (int o = 1; o < 512; o <<= 1) {
    int y = (t >= o) ? ts[t - o] : 0;
    __syncthreads();
    ts[t] += y;
    __syncthreads();
  }
  int excl = ts[t] - c;
  bucketStart[t] = excl;
  cursB1[t] = excl;
  if (t == 511) bucketStart[512] = ts[511];
}

// ---------------------------------------------------------------------------
// Phase B1 (AoS int2): bin entries into 512 buckets.
// ent1 packing: x = src | (local_node << 17), y = f32 val bits.
// ---------------------------------------------------------------------------
__global__ __launch_bounds__(256) void part1_kernel(
    const int* __restrict__ edge_row, const int* __restrict__ edge_col,
    const float* __restrict__ edge_val, int* __restrict__ cursB1,
    int2* __restrict__ ent1) {
  __shared__ int2 stg[NBUCK][B1_DEPTH];  // 56 KB
  __shared__ int scnt[NBUCK];
  const int tid = threadIdx.x;
  for (int i = tid; i < NBUCK; i += 256) scnt[i] = 0;
  __syncthreads();

  const int base = blockIdx.x * TILE_EDGES;
  #pragma unroll
  for (int k = 0; k < 8; ++k) {
    int e = base + k * 256 + tid;
    if (e < N_EDGES_C) {
      int r = edge_row[e];
      int c = edge_col[e];
      int vb = __float_as_int(edge_val[e]);
      int ub = (int)((unsigned)r / UB_NODES);
      int2 E1 = make_int2(c | ((r - ub * UB_NODES) << 17), vb);
      int s1 = atomicAdd(&scnt[ub], 1);
      if (s1 < B1_DEPTH) stg[ub][s1] = E1;
      else ent1[atomicAdd(&cursB1[ub], 1)] = E1;
      int ib = (int)((unsigned)c / IB_NODES);
      int2 E2 = make_int2(r | ((c - ib * IB_NODES) << 17), vb);
      ib += 256;
      int s2 = atomicAdd(&scnt[ib], 1);
      if (s2 < B1_DEPTH) stg[ib][s2] = E2;
      else ent1[atomicAdd(&cursB1[ib], 1)] = E2;
    }
  }
  __syncthreads();
  for (int i = tid; i < NBUCK; i += 256) {
    int cn = scnt[i];
    if (cn > B1_DEPTH) cn = B1_DEPTH;
    if (cn) {
      int p = atomicAdd(&cursB1[i], cn);
      for (int j = 0; j < cn; ++j) ent1[p + j] = stg[i][j];
    }
  }
}

// ---------------------------------------------------------------------------
// Phase B2: per-bucket node histogram + LDS scan -> off[] coalesced;
// scatter packed 4B entries via LDS cursor atomics.
// user-dest: P = (bf16(val)<<16) | src16
// item-dest: P = ((bf16(val)&0xFFFE | src&1)<<16) | (src>>1)
// ---------------------------------------------------------------------------
__global__ __launch_bounds__(256) void part2_kernel(
    const int* __restrict__ bucketStart, const int2* __restrict__ ent1,
    int* __restrict__ off, unsigned* __restrict__ entP) {
  __shared__ int lhist[512];
  __shared__ int lexcl[512];
  __shared__ int ps[256];
  const int b = blockIdx.x;
  const int tid = threadIdx.x;
  int nb, nodes;
  if (b < 256) {
    nb = b * UB_NODES;
    int e = (b + 1) * UB_NODES;
    if (e > N_USERS_C) e = N_USERS_C;
    nodes = e - nb;
  } else {
    nb = N_USERS_C + (b - 256) * IB_NODES;
    int e = N_USERS_C + (b - 255) * IB_NODES;
    if (e > N_NODES_C) e = N_NODES_C;
    nodes = e - nb;
  }
  const int start = bucketStart[b];
  const int end = bucketStart[b + 1];

  for (int i = tid; i < 512; i += 256) lhist[i] = 0;
  __syncthreads();

  for (int i = start + tid; i < end; i += 256)
    atomicAdd(&lhist[(unsigned)ent1[i].x >> 17], 1);
  __syncthreads();

  int a0 = lhist[2 * tid];
  int a1 = lhist[2 * tid + 1];
  ps[tid] = a0 + a1;
  __syncthreads();
  #pragma unroll
  for (int o = 1; o < 256; o <<= 1) {
    int y = (tid >= o) ? ps[tid - o] : 0;
    __syncthreads();
    ps[tid] += y;
    __syncthreads();
  }
  int e0 = ps[tid] - a0 - a1;
  lexcl[2 * tid] = e0;
  lexcl[2 * tid + 1] = e0 + a0;
  __syncthreads();

  for (int t = tid; t < nodes; t += 256) off[nb + t] = start + lexcl[t];
  if (b == NBUCK - 1 && tid == 0) off[N_NODES_C] = N_ENTRIES_C;

  for (int i = tid; i < 512; i += 256) lhist[i] = lexcl[i];
  __syncthreads();

  const bool isUser = (b < 256);
  for (int i = start + tid; i < end; i += 256) {
    int2 E = ent1[i];
    int local = (int)((unsigned)E.x >> 17);
    int src = E.x & 0x1FFFF;
    unsigned hb = bf16_bits(__int_as_float(E.y));
    unsigned P;
    if (isUser) {
      P = (hb << 16) | (unsigned)src;
    } else {
      P = (((hb & 0xFFFEu) | ((unsigned)src & 1u)) << 16) |
          ((unsigned)src >> 1);
    }
    int p = start + atomicAdd(&lhist[local], 1);
    entP[p] = P;
  }
}

// ---------------------------------------------------------------------------
// Gather: octet-wave, 16 rows in flight per wave (plain loads).
// Writes bf16 agg row into out's ego slot at float offset +4.
// ---------------------------------------------------------------------------
__device__ __forceinline__ void acc_row8(float* __restrict__ a, unsigned E,
                                         bool isUser,
                                         const ushort* __restrict__ tblU,
                                         const ushort* __restrict__ tblI,
                                         int ol) {
  unsigned src;
  float v;
  const ushort* t;
  if (isUser) {  // uniform branch per node
    src = E & 0xFFFFu;
    v = __uint_as_float(E & 0xFFFF0000u);
    t = tblI;
  } else {
    src = ((E & 0xFFFFu) << 1) | ((E >> 16) & 1u);
    v = __uint_as_float(E & 0xFFFE0000u);
    t = tblU;
  }
  uint4 q = *(const uint4*)(t + ((size_t)src << 6) + (ol << 3));
  a[0] += v * __uint_as_float(q.x << 16);
  a[1] += v * __uint_as_float(q.x & 0xFFFF0000u);
  a[2] += v * __uint_as_float(q.y << 16);
  a[3] += v * __uint_as_float(q.y & 0xFFFF0000u);
  a[4] += v * __uint_as_float(q.z << 16);
  a[5] += v * __uint_as_float(q.z & 0xFFFF0000u);
  a[6] += v * __uint_as_float(q.w << 16);
  a[7] += v * __uint_as_float(q.w & 0xFFFF0000u);
}

__global__ __launch_bounds__(256) void gather_kernel(
    const ushort* __restrict__ bf16tab, const int* __restrict__ off,
    const unsigned* __restrict__ entP, float* __restrict__ out) {
  const int lane = threadIdx.x & 63;
  const int og = lane >> 3;
  const int ol = lane & 7;
  const int wave0 = (blockIdx.x * 256 + threadIdx.x) >> 6;
  const int nWaves = gridDim.x * 4;
  const ushort* tblU = bf16tab;
  const ushort* tblI = bf16tab + (size_t)N_USERS_C * DIM_C;

  for (int n = wave0; n < N_NODES_C; n += nWaves) {
    const bool isUser = (n < N_USERS_C);
    int i = off[n] + og;
    const int end = off[n + 1];
    float a[8] = {0.f, 0.f, 0.f, 0.f, 0.f, 0.f, 0.f, 0.f};
    for (; i + 8 < end; i += 16) {
      unsigned E0 = entP[i];
      unsigned E1 = entP[i + 8];
      acc_row8(a, E0, isUser, tblU, tblI, ol);
      acc_row8(a, E1, isUser, tblU, tblI, ol);
    }
    if (i < end) acc_row8(a, entP[i], isUser, tblU, tblI, ol);

    #pragma unroll
    for (int k = 0; k < 8; ++k) {
      a[k] += __shfl_xor(a[k], 8);
      a[k] += __shfl_xor(a[k], 16);
      a[k] += __shfl_xor(a[k], 32);
    }
    if (lane < 8) {
      uint4 o;
      o.x = bf16_bits(a[0]) | (bf16_bits(a[1]) << 16);
      o.y = bf16_bits(a[2]) | (bf16_bits(a[3]) << 16);
      o.z = bf16_bits(a[4]) | (bf16_bits(a[5]) << 16);
      o.w = bf16_bits(a[6]) | (bf16_bits(a[7]) << 16);
      ((uint4*)(out + 4 + (size_t)n * 256))[ol] = o;
    }
  }
}

// ---------------------------------------------------------------------------
// Transform (MFMA): wave = 16 nodes, 24 MFMA, in-register epilogue,
// plain stores (L2 write-combining does the line coalescing).
// ---------------------------------------------------------------------------
__global__ __launch_bounds__(256) void transform_kernel(
    const float* __restrict__ user_emb, const float* __restrict__ item_emb,
    const uint4* __restrict__ wfragG, const float* __restrict__ bvec,
    float* __restrict__ out) {
  __shared__ uint4 Wf[24 * 64];  // 24 KB
  const int tid = threadIdx.x;
  for (int i = tid; i < 24 * 64; i += 256) Wf[i] = wfragG[i];
  __syncthreads();

  const int wave = tid >> 6;
  const int lane = tid & 63;
  const int nb = blockIdx.x * 64 + wave * 16;
  if (nb >= N_NODES_C) return;  // whole-wave guard (150000 % 16 == 0)
  const int q = lane >> 4;
  const int col = lane & 15;

  const uint4* aggp = (const uint4*)(out + 4 + (size_t)(nb + col) * 256);
  short8v A0 = as_short8(aggp[q]);
  short8v A1 = as_short8(aggp[q + 4]);

  for (int l = 0; l < 3; ++l) {
    f32x4 c[4];
    #pragma unroll
    for (int t = 0; t < 4; ++t) c[t] = (f32x4){0.f, 0.f, 0.f, 0.f};
    const uint4* wl = &Wf[l * 8 * 64];
    #pragma unroll
    for (int t = 0; t < 4; ++t) {
      c[t] = __builtin_amdgcn_mfma_f32_16x16x32_bf16(
          A0, as_short8(wl[(t * 2 + 0) * 64 + lane]), c[t], 0, 0, 0);
      c[t] = __builtin_amdgcn_mfma_f32_16x16x32_bf16(
          A1, as_short8(wl[(t * 2 + 1) * 64 + lane]), c[t], 0, 0, 0);
    }

    float sq[4] = {0.f, 0.f, 0.f, 0.f};
    #pragma unroll
    for (int t = 0; t < 4; ++t) {
      const float bt = bvec[l * DIM_C + t * 16 + col];
      #pragma unroll
      for (int r = 0; r < 4; ++r) {
        float v = c[t][r] + bt;
        v = (v >= 0.f) ? v : 0.2f * v;
        c[t][r] = v;
        sq[r] += v * v;
      }
    }
    #pragma unroll
    for (int r = 0; r < 4; ++r) {
      #pragma unroll
      for (int m = 1; m < 16; m <<= 1) sq[r] += __shfl_xor(sq[r], m);
      sq[r] = 1.0f / fmaxf(sqrtf(sq[r]), 1e-12f);
    }
    #pragma unroll
    for (int t = 0; t < 4; ++t) {
      #pragma unroll
      for (int r = 0; r < 4; ++r) {
        const int node = nb + q * 4 + r;
        out[1 + (size_t)node * 256 + (size_t)(l + 1) * 64 + t * 16 + col] =
            c[t][r] * sq[r];
      }
    }
  }

  for (int idx = lane; idx < 16 * DIM_C; idx += 64) {
    const int node = nb + (idx >> 6);
    const int cc = idx & 63;
    float e = (node < N_USERS_C)
                  ? user_emb[(size_t)node * DIM_C + cc]
                  : item_emb[(size_t)(node - N_USERS_C) * DIM_C + cc];
    out[1 + (size_t)node * 256 + cc] = e;
  }
}

// ---------------------------------------------------------------------------
// Loss: one wave per batch element; block-level LDS reduction; per-block
// partials to ws (NO global atomics).
// ---------------------------------------------------------------------------
__global__ __launch_bounds__(256) void loss_kernel(
    const float* __restrict__ out, const int* __restrict__ bu,
    const int* __restrict__ bp, const int* __restrict__ bn,
    float* __restrict__ part) {
  __shared__ float smf[4];
  __shared__ float srg[4];
  const int wave = threadIdx.x >> 6;
  const int lane = threadIdx.x & 63;
  const int j = blockIdx.x * 4 + wave;

  const float* urow = out + 1 + (size_t)bu[j] * 256;
  const float* prow = out + 1 + ((size_t)N_USERS_C + bp[j]) * 256;
  const float* nrow = out + 1 + ((size_t)N_USERS_C + bn[j]) * 256;

  float4 u = ((const float4*)urow)[lane];
  float4 pp = ((const float4*)prow)[lane];
  float4 nn = ((const float4*)nrow)[lane];

  float x = u.x * (pp.x - nn.x) + u.y * (pp.y - nn.y) +
            u.z * (pp.z - nn.z) + u.w * (pp.w - nn.w);
  float r = u.x * u.x + u.y * u.y + u.z * u.z + u.w * u.w +
            pp.x * pp.x + pp.y * pp.y + pp.z * pp.z + pp.w * pp.w +
            nn.x * nn.x + nn.y * nn.y + nn.z * nn.z + nn.w * nn.w;

  #pragma unroll
  for (int o = 32; o; o >>= 1) {
    x += __shfl_xor(x, o);
    r += __shfl_xor(r, o);
  }
  if (lane == 0) {
    float ls = fminf(x, 0.f) - log1pf(expf(-fabsf(x)));
    smf[wave] = -ls;
    srg[wave] = 0.5f * r;
  }
  __syncthreads();
  if (threadIdx.x == 0) {
    part[blockIdx.x] = smf[0] + smf[1] + smf[2] + smf[3];
    part[LOSS_NB + blockIdx.x] = srg[0] + srg[1] + srg[2] + srg[3];
  }
}

// ---------------------------------------------------------------------------
// Finalize: single block reduces 2x1024 partials -> out[0]
// ---------------------------------------------------------------------------
__global__ __launch_bounds__(256) void finalize_kernel(
    const float* __restrict__ part, float* __restrict__ out) {
  __shared__ float smf[4];
  __shared__ float srg[4];
  const int tid = threadIdx.x;
  float mf = 0.f, rg = 0.f;
  #pragma unroll
  for (int k = 0; k < LOSS_NB / 256; ++k) {
    mf += part[tid + k * 256];
    rg += part[LOSS_NB + tid + k * 256];
  }
  #pragma unroll
  for (int o = 32; o; o >>= 1) {
    mf += __shfl_xor(mf, o);
    rg += __shfl_xor(rg, o);
  }
  if ((tid & 63) == 0) {
    smf[tid >> 6] = mf;
    srg[tid >> 6] = rg;
  }
  __syncthreads();
  if (tid == 0) {
    float m = smf[0] + smf[1] + smf[2] + smf[3];
    float g = srg[0] + srg[1] + srg[2] + srg[3];
    out[0] = m / (float)BATCH_C + DECAY_C * g / (float)BATCH_C;
  }
}

// ---------------------------------------------------------------------------
extern "C" void kernel_launch(void* const* d_in, const int* in_sizes, int n_in,
                              void* d_out, int out_size, void* d_ws, size_t ws_size,
                              hipStream_t stream) {
  const float* user_emb = (const float*)d_in[0];
  const float* item_emb = (const float*)d_in[1];
  const float* edge_val = (const float*)d_in[2];
  const float* W        = (const float*)d_in[3];
  const float* bvec     = (const float*)d_in[4];
  const int* edge_row   = (const int*)d_in[5];
  const int* edge_col   = (const int*)d_in[6];
  const int* bu         = (const int*)d_in[7];
  const int* bp         = (const int*)d_in[8];
  const int* bn         = (const int*)d_in[9];

  float* out = (float*)d_out;
  int* ws = (int*)d_ws;
  int* off         = ws + WS_OFF;
  int* bcnt        = ws + WS_BCNT;
  int* bucketStart = ws + WS_BSTART;
  int* cursB1      = ws + WS_CB1;
  uint4* wfrag     = (uint4*)(ws + WS_WFRAG);
  float* part      = (float*)(ws + WS_PART);
  unsigned* entP   = (unsigned*)(ws + WS_ENT);
  ushort* bf16tab  = (ushort*)(ws + WS_BF16);
  int2* ent1       = (int2*)(out + ENT1_FLOAT_OFF);

  hipMemsetAsync(bcnt, 0, NBUCK * sizeof(int), stream);

  cast_kernel<<<(2400000 + 255) / 256, 256, 0, stream>>>(user_emb, item_emb,
                                                         bf16tab);
  wprep_kernel<<<6, 256, 0, stream>>>(W, wfrag);
  bucket_hist_kernel<<<NTILES, 256, 0, stream>>>(edge_row, edge_col, bcnt);
  scan512_kernel<<<1, 512, 0, stream>>>(bcnt, bucketStart, cursB1);
  part1_kernel<<<NTILES, 256, 0, stream>>>(edge_row, edge_col, edge_val,
                                           cursB1, ent1);
  part2_kernel<<<NBUCK, 256, 0, stream>>>(bucketStart, ent1, off, entP);
  gather_kernel<<<2048, 256, 0, stream>>>(bf16tab, off, entP, out);
  transform_kernel<<<(N_NODES_C + 63) / 64, 256, 0, stream>>>(
      user_emb, item_emb, wfrag, bvec, out);
  loss_kernel<<<LOSS_NB, 256, 0, stream>>>(out, bu, bp, bn, part);
  finalize_kernel<<<1, 256, 0, stream>>>(part, out);
}